// Round 6
// baseline (544.353 us; speedup 1.0000x reference)
//
#include <hip/hip_runtime.h>
#include <utility>
#include <cstddef>

// ---------------- compile-time Ivanic-Ruedenberg tables ----------------

struct Term { int o; int r; int a; float c; };
struct LTable { int n; Term t[1024]; };

constexpr double csqrt(double x) {
    if (x <= 0.0) return 0.0;
    double g = x < 1.0 ? 1.0 : x;
    for (int i = 0; i < 50; ++i) g = 0.5 * (g + x / g);
    return g;
}
constexpr int cabs_i(int x) { return x < 0 ? -x : x; }
constexpr int cmax_i(int a, int b) { return a > b ? a : b; }

constexpr void add_p(LTable& T, int o, double scale, int i, int a, int b, int l) {
    int lp = l - 1;
    int np = 2 * lp + 1;
    int row = i + 1;
    if (b == l) {
        T.t[T.n++] = Term{o, row * 3 + 2, (a + lp) * np + 2 * lp, (float)scale};
        T.t[T.n++] = Term{o, row * 3 + 0, (a + lp) * np + 0,      (float)(-scale)};
    } else if (b == -l) {
        T.t[T.n++] = Term{o, row * 3 + 2, (a + lp) * np + 0,      (float)scale};
        T.t[T.n++] = Term{o, row * 3 + 0, (a + lp) * np + 2 * lp, (float)scale};
    } else {
        T.t[T.n++] = Term{o, row * 3 + 1, (a + lp) * np + (b + lp), (float)scale};
    }
}

constexpr LTable ru_table(int l) {
    LTable T{};
    int n = 2 * l + 1;
    for (int m = -l; m <= l; ++m) {
        for (int mp = -l; mp <= l; ++mp) {
            double denom = (cabs_i(mp) == l) ? (double)((2 * l) * (2 * l - 1))
                                             : (double)((l + mp) * (l - mp));
            double d0 = (m == 0) ? 1.0 : 0.0;
            double u = csqrt((double)((l + m) * (l - m)) / denom);
            double v = 0.5 * csqrt((1.0 + d0) * (l + cabs_i(m) - 1) * (l + cabs_i(m)) / denom)
                       * (1.0 - 2.0 * d0);
            double w = -0.5 * csqrt((double)cmax_i(l - cabs_i(m) - 1, 0) * (l - cabs_i(m)) / denom)
                       * (1.0 - d0);
            int o = (m + l) * n + (mp + l);
            if (u != 0.0) add_p(T, o, u, 0, m, mp, l);
            if (v != 0.0) {
                if (m == 0) {
                    add_p(T, o, v, 1, 1, mp, l);
                    add_p(T, o, v, -1, -1, mp, l);
                } else if (m > 0) {
                    double s = (m == 1) ? csqrt(2.0) : 1.0;
                    add_p(T, o, v * s, 1, m - 1, mp, l);
                    if (m != 1) add_p(T, o, -v, -1, -m + 1, mp, l);
                } else {
                    if (m != -1) add_p(T, o, v, 1, m + 1, mp, l);
                    double s = (m == -1) ? csqrt(2.0) : 1.0;
                    add_p(T, o, v * s, -1, -m - 1, mp, l);
                }
            }
            if (w != 0.0) {
                if (m > 0) {
                    add_p(T, o, w, 1, m + 1, mp, l);
                    add_p(T, o, w, -1, -m - 1, mp, l);
                } else {
                    add_p(T, o, w, 1, m - 1, mp, l);
                    add_p(T, o, -w, -1, -m + 1, mp, l);
                }
            }
        }
    }
    return T;
}

inline constexpr LTable T2 = ru_table(2);
inline constexpr LTable T3 = ru_table(3);
inline constexpr LTable T4 = ru_table(4);

// terms for a given output entry are contiguous by construction (m-major, mp-minor)
template<const LTable& T>
constexpr int er_start(int e) {
    for (int i = 0; i < T.n; ++i) if (T.t[i].o == e) return i;
    return 0;
}
template<const LTable& T>
constexpr int er_cnt(int e) {
    int c = 0;
    for (int i = 0; i < T.n; ++i) if (T.t[i].o == e) ++c;
    return c;
}

template<const LTable& T, int S, size_t... K>
__device__ __forceinline__ float sum_terms(const float* __restrict__ R1,
                                           const float* __restrict__ P,
                                           std::index_sequence<K...>) {
    float a = 0.0f;
    ((a = fmaf(T.t[S + (int)K].c, R1[T.t[S + (int)K].r] * P[T.t[S + (int)K].a], a)), ...);
    return a;
}

// compute one entry of block l, optionally keep in array, stream ds_write to row
template<const LTable& T, int l, bool KEEP, int e>
__device__ __forceinline__ void level_one(const float* __restrict__ R1,
                                          const float* __restrict__ P,
                                          float* __restrict__ keep,
                                          float* __restrict__ row) {
    constexpr int S = er_start<T>(e);
    constexpr int C = er_cnt<T>(e);
    float v = sum_terms<T, S>(R1, P, std::make_index_sequence<C>{});
    if constexpr (KEEP) keep[e] = v;
    constexpr int d = 2 * l + 1;
    constexpr int r = e / d, c = e % d;
    constexpr int E625 = (l * l + r) * 25 + (l * l + c);  // ds_write imm offset
    row[E625] = v;
}

template<const LTable& T, int l, bool KEEP, size_t... E>
__device__ __forceinline__ void level(const float* __restrict__ R1,
                                      const float* __restrict__ P,
                                      float* __restrict__ keep,
                                      float* __restrict__ row,
                                      std::index_sequence<E...>) {
    (level_one<T, l, KEEP, (int)E>(R1, P, keep, row), ...);
}

template<size_t... E>
__device__ __forceinline__ void write_l1(const float* __restrict__ D1,
                                         float* __restrict__ row,
                                         std::index_sequence<E...>) {
    ((row[(1 + (int)E / 3) * 25 + (1 + (int)E % 3)] = D1[E]), ...);
}

// native clang vector type: required by __builtin_nontemporal_store
typedef float v4f __attribute__((ext_vector_type(4)));

// ---------------- fused, software-pipelined kernel ----------------
// Block: 256 threads = 256 points, 16 chunks of 16 points.
// Double-buffered LDS images: 2 x (16 x 625) floats = 80,000 B -> 2 blocks/CU.
// Iteration c: copy chunk c-1 from buf[(c-1)&1] (all threads, nontemporal v4f)
// CONCURRENT with scatter of chunk c into buf[c&1] (16 owner threads recompute
// their D from 4 live trig regs, streaming entries via compile-time-immediate
// ds_writes; bank = (17*p0+E)%32, 16 distinct banks -> conflict-free).
// One barrier per iteration; scatter VALU hides under the store drain.
// Structural zeros written once at block start; l=0's 1.0 written per scatter.

__global__ __launch_bounds__(256, 2)
void wigner_fused_kernel(const float* __restrict__ xyz, float* __restrict__ out, int Ntot) {
    __shared__ float buf[2][16 * 625];

    const int t = threadIdx.x;
    const int gp = blockIdx.x * 256 + t;

    float x = 0.0f, y = 0.0f, z = 1.0f;
    if (gp < Ntot) {
        x = xyz[3 * gp + 0];
        y = xyz[3 * gp + 1];
        z = xyz[3 * gp + 2];
    }

    // trig without trig: ct = vz (clipped), st = sqrt(1-ct^2), cp/sp from x,y
    const float r2 = x * x + y * y + z * z;
    const float rinv = rsqrtf(fmaxf(r2, 1e-24f));
    const float ct = fminf(fmaxf(z * rinv, -1.0f), 1.0f);
    const float st = sqrtf(fmaxf(1.0f - ct * ct, 0.0f));
    const float rxy2 = x * x + y * y;
    float cp = 1.0f, sp = 0.0f;
    if (rxy2 > 0.0f) {
        const float ri = rsqrtf(rxy2);
        cp = x * ri;
        sp = y * ri;
    }
    // only ct, st, cp, sp stay live across the chunk loop (4 VGPRs)

    // zero both images once (zero-structure slots never rewritten)
    {
        v4f* b4 = (v4f*)&buf[0][0];
        const v4f z4 = {0.0f, 0.0f, 0.0f, 0.0f};
#pragma unroll 4
        for (int k = t; k < 5000; k += 256) b4[k] = z4;
    }
    __syncthreads();

    const int p0 = t & 15;
    const int own = t >> 4;  // which chunk this thread's point belongs to
    const long long blk_f = (long long)blockIdx.x * 256 * 625;

#pragma unroll 1
    for (int c = 0; c <= 16; ++c) {
        // copy chunk c-1 (previous buffer) — issue stores first
        if (c > 0) {
            const int pc = c - 1;
            const int pbase = blockIdx.x * 256 + pc * 16;
            if (pbase < Ntot) {
                const int vp = min(16, Ntot - pbase);
                const long long out_f = blk_f + (long long)pc * 16 * 625;
                if (vp == 16) {
                    const v4f* src = (const v4f*)&buf[pc & 1][0];
                    v4f* dst = (v4f*)(out + out_f);
                    for (int k = t; k < 2500; k += 256) {
                        __builtin_nontemporal_store(src[k], dst + k);
                    }
                } else {
                    const float* srcf = &buf[pc & 1][0];
                    const int vf = vp * 625;
                    for (int k = t; k < vf; k += 256) {
                        out[out_f + k] = srcf[k];
                    }
                }
            }
        }

        // scatter chunk c into the other buffer (16 owner threads)
        if (c < 16 && own == c && gp < Ntot) {
            float* __restrict__ row = &buf[c & 1][0] + p0 * 625;
            row[0] = 1.0f;  // l=0 block

            // R1 in real-SH l=1 basis order (y,z,x), row-major 3x3
            float D1[9] = {cp,      0.0f, -sp,
                           st * sp, ct,   st * cp,
                           ct * sp, -st,  ct * cp};
            write_l1(D1, row, std::make_index_sequence<9>{});

            float D2[25];
            level<T2, 2, true>(D1, D1, D2, row, std::make_index_sequence<25>{});
            float D3[49];
            level<T3, 3, true>(D1, D2, D3, row, std::make_index_sequence<49>{});
            level<T4, 4, false>(D1, D3, nullptr, row, std::make_index_sequence<81>{});
        }

        __syncthreads();
    }
}

extern "C" void kernel_launch(void* const* d_in, const int* in_sizes, int n_in,
                              void* d_out, int out_size, void* d_ws, size_t ws_size,
                              hipStream_t stream) {
    const float* xyz = (const float*)d_in[0];
    float* out = (float*)d_out;
    const int N = in_sizes[0] / 3;
    const int blocks = (N + 255) / 256;
    hipLaunchKernelGGL(wigner_fused_kernel, dim3(blocks), dim3(256), 0, stream,
                       xyz, out, N);
}